// Round 1
// baseline (140.214 us; speedup 1.0000x reference)
//
#include <hip/hip_runtime.h>

#define NS 1024      // N samples
#define MM 64        // M patches
#define CC 4         // C compartments
#define NSTEPS 100
#define CLIPMAX 1e10f

// One block per sample n; 256 threads = 4 waves.
// LDS layouts (lane index fastest everywhere -> conflict-free):
//   RT[k][j]  = R[n,j,k]          (padded row 65)
//   G [j][i]  = beta[n]*Rt[n,i,j]/ntot[n,j]
//   rho[c][j]
__global__ __launch_bounds__(256, 4) void metapop_kernel(
    const float* __restrict__ R,     // (NS, MM, MM)
    const float* __restrict__ T,     // (NS, CC, CC)
    const float* __restrict__ rho0,  // (NS, MM, CC)
    const float* __restrict__ beta,  // (NS,)
    float* __restrict__ out)         // (NSTEPS, NS, MM, CC)
{
    const int n    = blockIdx.x;
    const int t    = threadIdx.x;
    const int lane = t & 63;
    const int w    = t >> 6;   // wave id 0..3

    __shared__ float RT[MM][MM + 1];
    __shared__ float G[MM][MM];
    __shared__ float rho[CC][MM];
    __shared__ float part[4][MM];
    __shared__ float pvec[MM];
    __shared__ float ninf[MM];
    __shared__ float Ts[CC][CC];
    __shared__ float ntot[MM];

    // ---- stage R[n] transposed, T[n], rho0[n] ----
    const float* Rn = R + (size_t)n * (MM * MM);
    for (int idx = t; idx < MM * MM; idx += 256) {
        int j = idx >> 6;          // row of R[n]
        int k = idx & 63;          // col
        RT[k][j] = Rn[idx];
    }
    if (t < CC * CC) Ts[t >> 2][t & 3] = T[n * (CC * CC) + t];
    {
        int j = t >> 2, c = t & 3;
        rho[c][j] = rho0[(size_t)n * (MM * CC) + t];
    }
    __syncthreads();

    // ---- ntot[k] = sum_j R[n,j,k] ----
    {
        float s = 0.f;
        #pragma unroll
        for (int jj = 0; jj < 16; ++jj) s += RT[lane][w * 16 + jj];
        part[w][lane] = s;
    }
    __syncthreads();
    if (t < MM) ntot[t] = part[0][t] + part[1][t] + part[2][t] + part[3][t];
    __syncthreads();

    // ---- gather G[j][i] = beta * R[(i&15)*64+j, (n&15)*4+(i>>4), n>>4] / ntot[j] ----
    // (full-reverse-transpose + reshape of R is a bijection on elements; L3 holds R)
    const float bet = beta[n];
    const int   r4  = (n & 15) << 2;
    const int   q   = n >> 4;
    for (int idx = t; idx < MM * MM; idx += 256) {
        int j = idx >> 6;
        int i = idx & 63;
        int s = ((i & 15) << 6) + j;
        int a = r4 + (i >> 4);
        float v = R[(size_t)s * (MM * MM) + a * MM + q];
        G[j][i] = bet * v / ntot[j];
    }
    __syncthreads();

    // ---- time loop ----
    const int tj = t >> 2, tc = t & 3;
    float* ob = out + (size_t)n * (MM * CC) + t;
    const size_t stepStride = (size_t)NS * MM * CC;

    for (int step = 0; step < NSTEPS; ++step) {
        // trajectory records PRE-update state; flat index j*4+c == t -> coalesced
        ob[(size_t)step * stepStride] = rho[tc][tj];

        // phase A: p[i] = 1 - prod_j (1 - rho1[i]*G[j][i]); 4-way split over j
        {
            float r1   = rho[1][lane];
            float prod = 1.f;
            #pragma unroll
            for (int jj = 0; jj < 16; ++jj)
                prod *= (1.f - r1 * G[w * 16 + jj][lane]);
            part[w][lane] = prod;
        }
        __syncthreads();
        if (t < MM) pvec[t] = 1.f - part[0][t] * part[1][t] * part[2][t] * part[3][t];
        __syncthreads();

        // phase B: ninf[j] = (1 - sum_c rho[j,c]) * sum_k R[n,j,k]*p[k]
        {
            float s = 0.f;
            #pragma unroll
            for (int kk = 0; kk < 16; ++kk) {
                int k = w * 16 + kk;
                s += RT[k][lane] * pvec[k];
            }
            part[w][lane] = s;
        }
        __syncthreads();
        if (t < MM) {
            float s  = part[0][t] + part[1][t] + part[2][t] + part[3][t];
            float sr = rho[0][t] + rho[1][t] + rho[2][t] + rho[3][t];
            ninf[t] = (1.f - sr) * s;
        }
        __syncthreads();

        // phase C: rho_new[j,l] = sum_k rho[j,k]*T[k,l] + ninf[j]*delta(l==0), clipped
        {
            float v = rho[0][lane] * Ts[0][w] + rho[1][lane] * Ts[1][w]
                    + rho[2][lane] * Ts[2][w] + rho[3][lane] * Ts[3][w];
            if (w == 0) v += ninf[lane];
            v = fminf(fmaxf(v, 0.f), CLIPMAX);
            __syncthreads();          // all reads of old rho done
            rho[w][lane] = v;
        }
        __syncthreads();
    }
}

extern "C" void kernel_launch(void* const* d_in, const int* in_sizes, int n_in,
                              void* d_out, int out_size, void* d_ws, size_t ws_size,
                              hipStream_t stream) {
    const float* R    = (const float*)d_in[0];
    const float* T    = (const float*)d_in[1];
    const float* rho0 = (const float*)d_in[2];
    const float* beta = (const float*)d_in[3];
    float* out = (float*)d_out;
    hipLaunchKernelGGL(metapop_kernel, dim3(NS), dim3(256), 0, stream,
                       R, T, rho0, beta, out);
}

// Round 2
// 81.203 us; speedup vs baseline: 1.7267x; 1.7267x over previous
//
#include <hip/hip_runtime.h>

#define NS 1024      // N samples
#define MM 64        // M patches
#define CC 4         // C compartments
#define NSTEPS 100
#define CLIPMAX 1e10f

// Broadcast lane k's value to all lanes via v_readlane (VALU, no LDS pipe).
__device__ __forceinline__ float rdlane(float v, int k) {
    return __uint_as_float(__builtin_amdgcn_readlane(__float_as_uint(v), k));
}

// One wave (64 threads) per sample. All state in registers:
//   Rrow[k] = R[n, lane, k]            (phase B matvec, lane = j)
//   Gcol[j] = beta * Rt[n, lane, j] / ntot[j]   (phase A product, lane = i)
//   rh[c]   = rho[n, lane, c]
//   tt[k][l]= T[n, k, l]               (uniform -> SGPRs)
// No __syncthreads, no LDS. p[k] broadcast via v_readlane in unrolled loops.
__global__ __launch_bounds__(64, 2) void metapop_kernel(
    const float* __restrict__ R,     // (NS, MM, MM)
    const float* __restrict__ T,     // (NS, CC, CC)
    const float* __restrict__ rho0,  // (NS, MM, CC)
    const float* __restrict__ beta,  // (NS,)
    float* __restrict__ out)         // (NSTEPS, NS, MM, CC)
{
    const int n    = blockIdx.x;
    const int lane = threadIdx.x;    // 0..63

    const float* Rn = R + (size_t)n * (MM * MM);

    // ---- Rrow: contiguous float4 loads (warms L1/L2 with R[n]) ----
    float Rrow[MM];
    {
        const float4* p4 = (const float4*)(Rn + lane * MM);
        #pragma unroll
        for (int k4 = 0; k4 < MM / 4; ++k4) {
            float4 v = p4[k4];
            Rrow[4*k4+0] = v.x; Rrow[4*k4+1] = v.y;
            Rrow[4*k4+2] = v.z; Rrow[4*k4+3] = v.w;
        }
    }

    // ---- ntot[lane] = sum_i R[n, i, lane]  (column sum; L1-hot after Rrow) ----
    float nt = 0.f;
    #pragma unroll
    for (int i = 0; i < MM; ++i) nt += Rn[i * MM + lane];
    const float binv = beta[n] / nt;     // lane j holds beta/ntot[j]

    // ---- Gcol[j] = Rt[n, lane, j] * (beta/ntot[j]) via the transpose bijection ----
    // Rt[n,i,j] = R[(i&15)*64+j, (n&15)*4+(i>>4), n>>4]  (verified in r1)
    float Gcol[MM];
    {
        const int r4    = (n & 15) << 2;
        const int q     = n >> 4;
        const int sbase = (lane & 15) << 6;
        const int a     = r4 + (lane >> 4);
        #pragma unroll
        for (int j = 0; j < MM; ++j) {
            float v = R[(size_t)(sbase + j) * (MM * MM) + a * MM + q];
            Gcol[j] = v * rdlane(binv, j);
        }
    }

    // ---- T[n] (uniform across lanes -> scalar regs) ----
    float tt[CC][CC];
    {
        const float* Tn = T + n * (CC * CC);
        #pragma unroll
        for (int k = 0; k < CC; ++k)
            #pragma unroll
            for (int l = 0; l < CC; ++l)
                tt[k][l] = Tn[k * CC + l];
    }

    // ---- rho0 ----
    float rh[CC];
    {
        float4 v = *(const float4*)(rho0 + (size_t)n * (MM * CC) + lane * CC);
        rh[0] = v.x; rh[1] = v.y; rh[2] = v.z; rh[3] = v.w;
    }

    float* ob = out + (size_t)n * (MM * CC) + lane * CC;
    const size_t stride = (size_t)NS * MM * CC;

    for (int step = 0; step < NSTEPS; ++step) {
        // trajectory records PRE-update state; fully coalesced float4
        *(float4*)(ob + (size_t)step * stride) =
            make_float4(rh[0], rh[1], rh[2], rh[3]);

        // phase A (lane = i): p = 1 - prod_j (1 - rho1 * Gcol[j]); 4 chains
        const float r1 = rh[1];
        float pr0 = 1.f, pr1 = 1.f, pr2 = 1.f, pr3 = 1.f;
        #pragma unroll
        for (int j = 0; j < 16; ++j) {
            pr0 *= 1.f - r1 * Gcol[j];
            pr1 *= 1.f - r1 * Gcol[j + 16];
            pr2 *= 1.f - r1 * Gcol[j + 32];
            pr3 *= 1.f - r1 * Gcol[j + 48];
        }
        const float p = 1.f - (pr0 * pr1) * (pr2 * pr3);

        // phase B (lane = j): s = sum_k R[n,j,k] * p[k]; p broadcast by readlane
        float s0 = 0.f, s1 = 0.f, s2 = 0.f, s3 = 0.f;
        #pragma unroll
        for (int k = 0; k < 16; ++k) {
            s0 += Rrow[k]      * rdlane(p, k);
            s1 += Rrow[k + 16] * rdlane(p, k + 16);
            s2 += Rrow[k + 32] * rdlane(p, k + 32);
            s3 += Rrow[k + 48] * rdlane(p, k + 48);
        }
        const float ssum = (s0 + s1) + (s2 + s3);
        const float sr   = (rh[0] + rh[1]) + (rh[2] + rh[3]);
        const float ninf = (1.f - sr) * ssum;

        // phase C (all lane-local): rho_new[l] = sum_k rho[k]*T[k,l] (+ninf at l=0)
        float nr[CC];
        #pragma unroll
        for (int l = 0; l < CC; ++l) {
            float v = rh[0] * tt[0][l] + rh[1] * tt[1][l]
                    + rh[2] * tt[2][l] + rh[3] * tt[3][l];
            if (l == 0) v += ninf;
            nr[l] = fminf(fmaxf(v, 0.f), CLIPMAX);
        }
        #pragma unroll
        for (int l = 0; l < CC; ++l) rh[l] = nr[l];
    }
}

extern "C" void kernel_launch(void* const* d_in, const int* in_sizes, int n_in,
                              void* d_out, int out_size, void* d_ws, size_t ws_size,
                              hipStream_t stream) {
    const float* R    = (const float*)d_in[0];
    const float* T    = (const float*)d_in[1];
    const float* rho0 = (const float*)d_in[2];
    const float* beta = (const float*)d_in[3];
    float* out = (float*)d_out;
    hipLaunchKernelGGL(metapop_kernel, dim3(NS), dim3(64), 0, stream,
                       R, T, rho0, beta, out);
}

// Round 3
// 79.023 us; speedup vs baseline: 1.7743x; 1.0276x over previous
//
#include <hip/hip_runtime.h>

#define NS 1024      // N samples
#define MM 64        // M patches
#define CC 4         // C compartments
#define NSTEPS 100
#define CLIPMAX 1e10f

// Broadcast lane k's value to all lanes via v_readlane (VALU, no LDS pipe).
__device__ __forceinline__ float rdlane(float v, int k) {
    return __uint_as_float(__builtin_amdgcn_readlane(__float_as_uint(v), k));
}

// One wave (64 threads) per sample. All state in registers:
//   Rrow[k] = R[n, lane, k]                      (phase B matvec, lane = j)
//   Gcol[j] = beta * Rt[n, lane, j] / ntot[j]    (phase A product, lane = i)
// Registers are PINNED with opaque asm so the compiler cannot sink the loads
// into the time loop (r2 showed it rematerializes them -> L1-latency-bound
// at 1 wave/SIMD with no TLP to hide it).
__global__ __launch_bounds__(64, 1) void metapop_kernel(
    const float* __restrict__ R,     // (NS, MM, MM)
    const float* __restrict__ T,     // (NS, CC, CC)
    const float* __restrict__ rho0,  // (NS, MM, CC)
    const float* __restrict__ beta,  // (NS,)
    float* __restrict__ out)         // (NSTEPS, NS, MM, CC)
{
    const int n    = blockIdx.x;
    const int lane = threadIdx.x;    // 0..63

    const float* Rn = R + (size_t)n * (MM * MM);

    // ---- Rrow: contiguous float4 loads ----
    float Rrow[MM];
    {
        const float4* p4 = (const float4*)(Rn + lane * MM);
        #pragma unroll
        for (int k4 = 0; k4 < MM / 4; ++k4) {
            float4 v = p4[k4];
            Rrow[4*k4+0] = v.x; Rrow[4*k4+1] = v.y;
            Rrow[4*k4+2] = v.z; Rrow[4*k4+3] = v.w;
        }
    }

    // ---- ntot[lane] = sum_i R[n, i, lane]  (column sum; L1-hot after Rrow) ----
    float nt = 0.f;
    #pragma unroll
    for (int i = 0; i < MM; ++i) nt += Rn[i * MM + lane];
    const float binv = beta[n] / nt;     // lane j holds beta/ntot[j]

    // ---- Gcol[j] = Rt[n, lane, j] * (beta/ntot[j]) via the transpose bijection ----
    // Rt[n,i,j] = R[(i&15)*64+j, (n&15)*4+(i>>4), n>>4]
    float Gcol[MM];
    {
        const int r4    = (n & 15) << 2;
        const int q     = n >> 4;
        const int sbase = (lane & 15) << 6;
        const int a     = r4 + (lane >> 4);
        #pragma unroll
        for (int j = 0; j < MM; ++j) {
            float v = R[(size_t)(sbase + j) * (MM * MM) + a * MM + q];
            Gcol[j] = v * rdlane(binv, j);
        }
    }

    // ---- PIN the 128 state registers: opaque to the optimizer, zero cost ----
    #pragma unroll
    for (int k = 0; k < MM; ++k) asm volatile("" : "+v"(Rrow[k]));
    #pragma unroll
    for (int j = 0; j < MM; ++j) asm volatile("" : "+v"(Gcol[j]));

    // ---- T[n] (uniform across lanes -> scalar regs) ----
    float tt[CC][CC];
    {
        const float* Tn = T + n * (CC * CC);
        #pragma unroll
        for (int k = 0; k < CC; ++k)
            #pragma unroll
            for (int l = 0; l < CC; ++l)
                tt[k][l] = Tn[k * CC + l];
    }

    // ---- rho0 ----
    float rh[CC];
    {
        float4 v = *(const float4*)(rho0 + (size_t)n * (MM * CC) + lane * CC);
        rh[0] = v.x; rh[1] = v.y; rh[2] = v.z; rh[3] = v.w;
    }

    float* ob = out + (size_t)n * (MM * CC) + lane * CC;
    const size_t stride = (size_t)NS * MM * CC;

    for (int step = 0; step < NSTEPS; ++step) {
        // trajectory records PRE-update state; fully coalesced float4
        *(float4*)(ob + (size_t)step * stride) =
            make_float4(rh[0], rh[1], rh[2], rh[3]);

        // phase A (lane = i): p = 1 - prod_j (1 - rho1 * Gcol[j]); 4 chains
        const float r1 = rh[1];
        float pr0 = 1.f, pr1 = 1.f, pr2 = 1.f, pr3 = 1.f;
        #pragma unroll
        for (int j = 0; j < 16; ++j) {
            pr0 *= 1.f - r1 * Gcol[j];
            pr1 *= 1.f - r1 * Gcol[j + 16];
            pr2 *= 1.f - r1 * Gcol[j + 32];
            pr3 *= 1.f - r1 * Gcol[j + 48];
        }
        const float p = 1.f - (pr0 * pr1) * (pr2 * pr3);

        // phase B (lane = j): s = sum_k R[n,j,k] * p[k]; p broadcast by readlane
        float s0 = 0.f, s1 = 0.f, s2 = 0.f, s3 = 0.f;
        #pragma unroll
        for (int k = 0; k < 16; ++k) {
            s0 += Rrow[k]      * rdlane(p, k);
            s1 += Rrow[k + 16] * rdlane(p, k + 16);
            s2 += Rrow[k + 32] * rdlane(p, k + 32);
            s3 += Rrow[k + 48] * rdlane(p, k + 48);
        }
        const float ssum = (s0 + s1) + (s2 + s3);
        const float sr   = (rh[0] + rh[1]) + (rh[2] + rh[3]);
        const float ninf = (1.f - sr) * ssum;

        // phase C (all lane-local): rho_new[l] = sum_k rho[k]*T[k,l] (+ninf at l=0)
        float nr[CC];
        #pragma unroll
        for (int l = 0; l < CC; ++l) {
            float v = rh[0] * tt[0][l] + rh[1] * tt[1][l]
                    + rh[2] * tt[2][l] + rh[3] * tt[3][l];
            if (l == 0) v += ninf;
            nr[l] = fminf(fmaxf(v, 0.f), CLIPMAX);
        }
        #pragma unroll
        for (int l = 0; l < CC; ++l) rh[l] = nr[l];
    }
}

extern "C" void kernel_launch(void* const* d_in, const int* in_sizes, int n_in,
                              void* d_out, int out_size, void* d_ws, size_t ws_size,
                              hipStream_t stream) {
    const float* R    = (const float*)d_in[0];
    const float* T    = (const float*)d_in[1];
    const float* rho0 = (const float*)d_in[2];
    const float* beta = (const float*)d_in[3];
    float* out = (float*)d_out;
    hipLaunchKernelGGL(metapop_kernel, dim3(NS), dim3(64), 0, stream,
                       R, T, rho0, beta, out);
}